// Round 8
// baseline (615.981 us; speedup 1.0000x reference)
//
#include <hip/hip_runtime.h>
#include <math.h>

// Problem constants
#define HH 2048
#define EE 64
#define TOPK 8
#define NT 16384
#define KC 16            // K per chunk (1 float4 per thread per array staging)
#define LDH 20           // LDS row stride (floats): 16B-aligned rows, <=2-way banks
#define BT 32            // tokens per WG in reduce kernel
#define LS 68            // slog row stride in reduce kernel

// ---------------- Kernel 1: fp32 GEMM partial, 64x64 tile, 4x4/thread ----------------
// grid (256, S); block 256. Thread (tx,ty): tokens ty+16i, experts tx+16j.
// Per k-quad: ha[4]+wb[4] via ds_read_b128 (8 reads serving 64 FMAs = best
// operand-delivery ratio of rounds 1-7; R5's scalar-w and R6/7's broadcast-w
// both stalled at ~2950 cyc/chunk on w delivery).
// KC=16 + __launch_bounds__(256,4): cap VGPR at 128 -> 4 waves/SIMD (m69
// halving model). R4's identical math at VGPR 152 ran 1-2 waves/SIMD (197 us).
// R3's spill disaster was natural ~152 vs cap 128; this body is slimmer
// (half prefetch, half staging, 4 quads not 8) -> expect ~100-110 natural.
// K ascending per accumulator (c up, kk up, .xyzw) -> bitwise-identical
// partials to rounds 4-7 (all produced absmax 4.88e-4).
__global__ __launch_bounds__(256, 4) void gemm_t44(
    const float* __restrict__ x,   // [NT, H]
    const float* __restrict__ w,   // [E, H]
    float* __restrict__ P,         // [S][NT, E]
    int kper)
{
    __shared__ float sh[2][64 * LDH];
    __shared__ float sw[2][64 * LDH];

    const int t  = threadIdx.x;
    const int tx = t & 15;         // expert lane: experts tx+16j
    const int ty = t >> 4;         // token lane:  tokens  ty+16i
    const int tok0 = blockIdx.x * 64;
    const int s    = blockIdx.y;
    const int k0   = s * kper;
    const int nch  = kper / KC;    // 32 at S=4

    // staging: thread t -> row t>>2 (0..63), float4 col (t&3)*4
    const int srow = t >> 2;
    const int sc4  = (t & 3) * 4;

    float acc[4][4];
#pragma unroll
    for (int i = 0; i < 4; ++i)
#pragma unroll
        for (int j = 0; j < 4; ++j) acc[i][j] = 0.f;

    float4 px, pw;

    // ---- prologue: chunk 0 ----
    px = *(const float4*)(x + (size_t)(tok0 + srow) * HH + k0 + sc4);
    pw = *(const float4*)(w + (size_t)srow * HH + k0 + sc4);
    *(float4*)&sh[0][srow * LDH + sc4] = px;
    *(float4*)&sw[0][srow * LDH + sc4] = pw;
    __syncthreads();

    for (int c = 0; c < nch; ++c) {
        const int buf = c & 1;
        const bool more = (c + 1 < nch);
        if (more) {
            const int kn = k0 + (c + 1) * KC;
            px = *(const float4*)(x + (size_t)(tok0 + srow) * HH + kn + sc4);
            pw = *(const float4*)(w + (size_t)srow * HH + kn + sc4);
        }

#pragma unroll
        for (int kk = 0; kk < KC; kk += 4) {
            float4 ha[4], wb[4];
#pragma unroll
            for (int i = 0; i < 4; ++i)
                ha[i] = *(const float4*)&sh[buf][(ty + 16 * i) * LDH + kk];
#pragma unroll
            for (int j = 0; j < 4; ++j)
                wb[j] = *(const float4*)&sw[buf][(tx + 16 * j) * LDH + kk];
#pragma unroll
            for (int i = 0; i < 4; ++i)
#pragma unroll
                for (int j = 0; j < 4; ++j) {
                    acc[i][j] = fmaf(ha[i].x, wb[j].x, acc[i][j]);
                    acc[i][j] = fmaf(ha[i].y, wb[j].y, acc[i][j]);
                    acc[i][j] = fmaf(ha[i].z, wb[j].z, acc[i][j]);
                    acc[i][j] = fmaf(ha[i].w, wb[j].w, acc[i][j]);
                }
        }

        if (more) {
            const int nbuf = (c + 1) & 1;
            *(float4*)&sh[nbuf][srow * LDH + sc4] = px;
            *(float4*)&sw[nbuf][srow * LDH + sc4] = pw;
        }
        __syncthreads();
    }

    // ---- write partials: P[s][tok0 + ty+16i][tx+16j] ----
    float* Pw = P + ((size_t)s * NT + tok0) * EE;
#pragma unroll
    for (int i = 0; i < 4; ++i)
#pragma unroll
        for (int j = 0; j < 4; ++j)
            Pw[(ty + 16 * i) * EE + tx + 16 * j] = acc[i][j];
}

// ---------------- Kernel 2: reduce S slices + logits + top-8 softmax ----------------
// grid 512, block 128 (verbatim from rounds 6/7 — proven correct).
__global__ __launch_bounds__(128, 1) void reduce_topk(
    const float* __restrict__ P,   // [S][NT, E]
    int S,
    float* __restrict__ out_logits,
    float* __restrict__ out_wts,
    float* __restrict__ out_idx)
{
    __shared__ float slog[BT * LS];

    const int t    = threadIdx.x;
    const int tok0 = blockIdx.x * BT;
    const int tr   = t >> 2;        // token row 0..31
    const int p    = t & 3;         // expert 16-block

    float v[16];
#pragma unroll
    for (int c = 0; c < 4; ++c) {
        float4 a = *(const float4*)(P + ((size_t)(tok0 + tr)) * EE + 16 * p + 4 * c);
        v[4 * c + 0] = a.x; v[4 * c + 1] = a.y; v[4 * c + 2] = a.z; v[4 * c + 3] = a.w;
    }
    for (int s = 1; s < S; ++s) {
#pragma unroll
        for (int c = 0; c < 4; ++c) {
            float4 a = *(const float4*)(P + ((size_t)s * NT + tok0 + tr) * EE + 16 * p + 4 * c);
            v[4 * c + 0] += a.x; v[4 * c + 1] += a.y; v[4 * c + 2] += a.z; v[4 * c + 3] += a.w;
        }
    }

#pragma unroll
    for (int c = 0; c < 4; ++c) {
        float4 a;
        a.x = v[4 * c + 0]; a.y = v[4 * c + 1]; a.z = v[4 * c + 2]; a.w = v[4 * c + 3];
        *(float4*)(out_logits + (size_t)(tok0 + tr) * EE + 16 * p + 4 * c) = a;
        *(float4*)&slog[tr * LS + 16 * p + 4 * c] = a;
    }
    __syncthreads();

    if (t < BT) {
        float tv[TOPK];
        int   ti[TOPK];
#pragma unroll
        for (int q = 0; q < TOPK; ++q) { tv[q] = -INFINITY; ti[q] = 0; }

        for (int e = 0; e < EE; ++e) {
            const float val = slog[t * LS + e];
            if (val > tv[TOPK - 1]) {
                tv[TOPK - 1] = val;
                ti[TOPK - 1] = e;
#pragma unroll
                for (int q = TOPK - 1; q > 0; --q) {
                    if (tv[q] > tv[q - 1]) {   // strict: lowest-index-first on ties
                        float fv = tv[q]; tv[q] = tv[q - 1]; tv[q - 1] = fv;
                        int   fi = ti[q]; ti[q] = ti[q - 1]; ti[q - 1] = fi;
                    }
                }
            }
        }

        const float m = tv[0];
        float ew[TOPK];
        float sum = 0.f;
#pragma unroll
        for (int q = 0; q < TOPK; ++q) { ew[q] = expf(tv[q] - m); sum += ew[q]; }
        const float inv = 1.f / sum;

        const size_t tok = (size_t)(tok0 + t);
        float4 w0, w1, i0, i1;
        w0.x = ew[0] * inv; w0.y = ew[1] * inv; w0.z = ew[2] * inv; w0.w = ew[3] * inv;
        w1.x = ew[4] * inv; w1.y = ew[5] * inv; w1.z = ew[6] * inv; w1.w = ew[7] * inv;
        i0.x = (float)ti[0]; i0.y = (float)ti[1]; i0.z = (float)ti[2]; i0.w = (float)ti[3];
        i1.x = (float)ti[4]; i1.y = (float)ti[5]; i1.z = (float)ti[6]; i1.w = (float)ti[7];
        *(float4*)(out_wts + tok * TOPK)     = w0;
        *(float4*)(out_wts + tok * TOPK + 4) = w1;
        *(float4*)(out_idx + tok * TOPK)     = i0;
        *(float4*)(out_idx + tok * TOPK + 4) = i1;
    }
}

extern "C" void kernel_launch(void* const* d_in, const int* in_sizes, int n_in,
                              void* d_out, int out_size, void* d_ws, size_t ws_size,
                              hipStream_t stream) {
    const float* x = (const float*)d_in[0];   // hidden_states [4,4096,2048] fp32
    const float* w = (const float*)d_in[1];   // gate_w [64,2048] fp32
    float* out        = (float*)d_out;
    float* out_logits = out;                              // 16384*64
    float* out_wts    = out + (size_t)NT * EE;            // 16384*8
    float* out_idx    = out_wts + (size_t)NT * TOPK;      // 16384*8

    const size_t sliceB = (size_t)NT * EE * sizeof(float);   // 4.19 MB per slice
    int S;
    float* P;
    if (ws_size >= 4 * sliceB)      { S = 4; P = (float*)d_ws; }
    else if (ws_size >= 2 * sliceB) { S = 2; P = (float*)d_ws; }
    else                            { S = 1; P = out_logits; }

    dim3 grid1(NT / 64, S), block1(256);
    hipLaunchKernelGGL(gemm_t44, grid1, block1, 0, stream, x, w, P, HH / S);

    dim3 grid2(NT / BT), block2(128);
    hipLaunchKernelGGL(reduce_topk, grid2, block2, 0, stream,
                       P, S, out_logits, out_wts, out_idx);
}

// Round 9
// 504.799 us; speedup vs baseline: 1.2202x; 1.2202x over previous
//
#include <hip/hip_runtime.h>
#include <math.h>

// Problem constants
#define HH 2048
#define EE 64
#define TOPK 8
#define NT 16384
#define BT 64            // tokens per WG (kernel1 tile: 64 tokens x 64 experts)
#define KC 32            // K chunk
#define LDH 36           // LDS row stride (floats): measured best (5.2M conflicts vs 10.5M at 20)
#define BTR 32           // tokens per WG in reduce kernel
#define LS 68            // slog row stride in reduce kernel

// ---------------- Kernel 1: fp32 GEMM partial over a K-range ----------------
// grid (256, S); block 256. WG (m, s): tokens m*64..+64, experts 0..64,
// K in [s*kper, (s+1)*kper). Writes partials P[s][token][expert].
//
// LAUNCH-BOUNDS HISTORY (the whole game on this body):
//   (256,1): VGPR 152, no spill, ~1 wave/SIMD resident -> 197 us  [R4]
//   (256,4): compiler clamps to 64 VGPR -> massive scratch spill
//            (WRITE_SIZE ~1-3 GB, VALUBusy 4-10%) -> 476-1085 us  [R3, R8]
//   (256,2): cap ~128 VGPR -- enough for this body with relaxed
//            scheduling, no spill, 2-3 waves/SIMD.                [this round]
__global__ __launch_bounds__(256, 2) void gemm_part(
    const float* __restrict__ x,   // [NT, H]
    const float* __restrict__ w,   // [E, H]
    float* __restrict__ P,         // [S][NT, E]
    int kper)
{
    __shared__ float sh[2][BT * LDH];
    __shared__ float sw[2][BT * LDH];

    const int t  = threadIdx.x;
    const int tx = t & 15;         // expert base lane: experts tx+16j
    const int ty = t >> 4;         // token base lane:  tokens  ty+16i
    const int tok0 = blockIdx.x * BT;
    const int s    = blockIdx.y;
    const int k0   = s * kper;
    const int nch  = kper / KC;

    // staging role: thread t covers rows {t>>3, (t>>3)+32}, float4 col (t&7)*4
    const int srow = t >> 3;
    const int sc4  = (t & 7) * 4;

    float acc[4][4];
#pragma unroll
    for (int i = 0; i < 4; ++i)
#pragma unroll
        for (int j = 0; j < 4; ++j) acc[i][j] = 0.f;

    float4 px[2], pw[2];

    // ---- prologue: load chunk 0 ----
#pragma unroll
    for (int r = 0; r < 2; ++r) {
        const int row = srow + 32 * r;
        px[r] = *(const float4*)(x + (size_t)(tok0 + row) * HH + k0 + sc4);
        pw[r] = *(const float4*)(w + (size_t)row * HH + k0 + sc4);
    }
#pragma unroll
    for (int r = 0; r < 2; ++r) {
        const int row = srow + 32 * r;
        *(float4*)&sh[0][row * LDH + sc4] = px[r];
        *(float4*)&sw[0][row * LDH + sc4] = pw[r];
    }
    __syncthreads();

    // ---- main K loop: double-buffered, 1 barrier per chunk ----
    for (int c = 0; c < nch; ++c) {
        const int buf = c & 1;
        const bool more = (c + 1 < nch);
        if (more) {
            const int kn = k0 + (c + 1) * KC;
#pragma unroll
            for (int r = 0; r < 2; ++r) {
                const int row = srow + 32 * r;
                px[r] = *(const float4*)(x + (size_t)(tok0 + row) * HH + kn + sc4);
                pw[r] = *(const float4*)(w + (size_t)row * HH + kn + sc4);
            }
        }

#pragma unroll
        for (int kk = 0; kk < KC; kk += 4) {
            float4 ha[4], wb[4];
#pragma unroll
            for (int i = 0; i < 4; ++i)
                ha[i] = *(const float4*)&sh[buf][(ty + 16 * i) * LDH + kk];
#pragma unroll
            for (int j = 0; j < 4; ++j)
                wb[j] = *(const float4*)&sw[buf][(tx + 16 * j) * LDH + kk];
#pragma unroll
            for (int i = 0; i < 4; ++i)
#pragma unroll
                for (int j = 0; j < 4; ++j) {
                    acc[i][j] = fmaf(ha[i].x, wb[j].x, acc[i][j]);
                    acc[i][j] = fmaf(ha[i].y, wb[j].y, acc[i][j]);
                    acc[i][j] = fmaf(ha[i].z, wb[j].z, acc[i][j]);
                    acc[i][j] = fmaf(ha[i].w, wb[j].w, acc[i][j]);
                }
        }

        if (more) {
            const int nbuf = (c + 1) & 1;
#pragma unroll
            for (int r = 0; r < 2; ++r) {
                const int row = srow + 32 * r;
                *(float4*)&sh[nbuf][row * LDH + sc4] = px[r];
                *(float4*)&sw[nbuf][row * LDH + sc4] = pw[r];
            }
        }
        __syncthreads();
    }

    // ---- write partials: P[s][tok0 + ty+16i][tx+16j] ----
    float* Pw = P + ((size_t)s * NT + tok0) * EE;
#pragma unroll
    for (int i = 0; i < 4; ++i)
#pragma unroll
        for (int j = 0; j < 4; ++j)
            Pw[(ty + 16 * i) * EE + tx + 16 * j] = acc[i][j];
}

// ---------------- Kernel 2: reduce S slices + logits + top-8 softmax ----------------
// grid 512, block 128 (verbatim from rounds 6-8 — proven correct).
__global__ __launch_bounds__(128, 1) void reduce_topk(
    const float* __restrict__ P,   // [S][NT, E]
    int S,
    float* __restrict__ out_logits,
    float* __restrict__ out_wts,
    float* __restrict__ out_idx)
{
    __shared__ float slog[BTR * LS];

    const int t    = threadIdx.x;
    const int tok0 = blockIdx.x * BTR;
    const int tr   = t >> 2;        // token row 0..31
    const int p    = t & 3;         // expert 16-block

    float v[16];
#pragma unroll
    for (int c = 0; c < 4; ++c) {
        float4 a = *(const float4*)(P + ((size_t)(tok0 + tr)) * EE + 16 * p + 4 * c);
        v[4 * c + 0] = a.x; v[4 * c + 1] = a.y; v[4 * c + 2] = a.z; v[4 * c + 3] = a.w;
    }
    for (int s = 1; s < S; ++s) {
#pragma unroll
        for (int c = 0; c < 4; ++c) {
            float4 a = *(const float4*)(P + ((size_t)s * NT + tok0 + tr) * EE + 16 * p + 4 * c);
            v[4 * c + 0] += a.x; v[4 * c + 1] += a.y; v[4 * c + 2] += a.z; v[4 * c + 3] += a.w;
        }
    }

#pragma unroll
    for (int c = 0; c < 4; ++c) {
        float4 a;
        a.x = v[4 * c + 0]; a.y = v[4 * c + 1]; a.z = v[4 * c + 2]; a.w = v[4 * c + 3];
        *(float4*)(out_logits + (size_t)(tok0 + tr) * EE + 16 * p + 4 * c) = a;
        *(float4*)&slog[tr * LS + 16 * p + 4 * c] = a;
    }
    __syncthreads();

    if (t < BTR) {
        float tv[TOPK];
        int   ti[TOPK];
#pragma unroll
        for (int q = 0; q < TOPK; ++q) { tv[q] = -INFINITY; ti[q] = 0; }

        for (int e = 0; e < EE; ++e) {
            const float val = slog[t * LS + e];
            if (val > tv[TOPK - 1]) {
                tv[TOPK - 1] = val;
                ti[TOPK - 1] = e;
#pragma unroll
                for (int q = TOPK - 1; q > 0; --q) {
                    if (tv[q] > tv[q - 1]) {   // strict: lowest-index-first on ties
                        float fv = tv[q]; tv[q] = tv[q - 1]; tv[q - 1] = fv;
                        int   fi = ti[q]; ti[q] = ti[q - 1]; ti[q - 1] = fi;
                    }
                }
            }
        }

        const float m = tv[0];
        float ew[TOPK];
        float sum = 0.f;
#pragma unroll
        for (int q = 0; q < TOPK; ++q) { ew[q] = expf(tv[q] - m); sum += ew[q]; }
        const float inv = 1.f / sum;

        const size_t tok = (size_t)(tok0 + t);
        float4 w0, w1, i0, i1;
        w0.x = ew[0] * inv; w0.y = ew[1] * inv; w0.z = ew[2] * inv; w0.w = ew[3] * inv;
        w1.x = ew[4] * inv; w1.y = ew[5] * inv; w1.z = ew[6] * inv; w1.w = ew[7] * inv;
        i0.x = (float)ti[0]; i0.y = (float)ti[1]; i0.z = (float)ti[2]; i0.w = (float)ti[3];
        i1.x = (float)ti[4]; i1.y = (float)ti[5]; i1.z = (float)ti[6]; i1.w = (float)ti[7];
        *(float4*)(out_wts + tok * TOPK)     = w0;
        *(float4*)(out_wts + tok * TOPK + 4) = w1;
        *(float4*)(out_idx + tok * TOPK)     = i0;
        *(float4*)(out_idx + tok * TOPK + 4) = i1;
    }
}

extern "C" void kernel_launch(void* const* d_in, const int* in_sizes, int n_in,
                              void* d_out, int out_size, void* d_ws, size_t ws_size,
                              hipStream_t stream) {
    const float* x = (const float*)d_in[0];   // hidden_states [4,4096,2048] fp32
    const float* w = (const float*)d_in[1];   // gate_w [64,2048] fp32
    float* out        = (float*)d_out;
    float* out_logits = out;                              // 16384*64
    float* out_wts    = out + (size_t)NT * EE;            // 16384*8
    float* out_idx    = out_wts + (size_t)NT * TOPK;      // 16384*8

    const size_t sliceB = (size_t)NT * EE * sizeof(float);   // 4.19 MB per slice
    int S;
    float* P;
    if (ws_size >= 4 * sliceB)      { S = 4; P = (float*)d_ws; }
    else if (ws_size >= 2 * sliceB) { S = 2; P = (float*)d_ws; }
    else                            { S = 1; P = out_logits; }

    dim3 grid1(NT / BT, S), block1(256);
    hipLaunchKernelGGL(gemm_part, grid1, block1, 0, stream, x, w, P, HH / S);

    dim3 grid2(NT / BTR), block2(128);
    hipLaunchKernelGGL(reduce_topk, grid2, block2, 0, stream,
                       P, S, out_logits, out_wts, out_idx);
}